// Round 7
// baseline (546.916 us; speedup 1.0000x reference)
//
#include <hip/hip_runtime.h>
#include <cstdint>

#define S_FRAMES 64
#define NPF      147456           // 384*384
#define TOT      (S_FRAMES * NPF) // 9437184
#define NBINS    4096
#define R1       73728u           // valid = c >= sorted[R1] (== c >= median, exactly)
#define NB1      512              // 8 blocks/frame for the big passes
#define CHK      (NPF / 8)        // 18432 points per chunk
#define G4       (CHK / 4)        // 4608 float4 groups per chunk
#define CAPC     512
#define CAPR     4096
#define WORDS_BM 9344             // 8192 (dim64,λ40) + 1024 (dim32,λ20) + 128 (dim16,λ10)

// ---- workspace layout (bytes) ----
#define OFF_HSL  0                                   // 512*4096*4 = 8 MB hist slices
#define OFF_CSL  (OFF_HSL + NB1 * NBINS * 4)         // 512*384*4 coarse minmax slices
#define OFF_PBD  (OFF_CSL + NB1 * 384 * 4)           // 512*2 f64 sums partials
#define OFF_PBC  (OFF_PBD + NB1 * 16)                // 512 u32 count partials
#define OFF_CTR  (OFF_PBC + NB1 * 4)                 // 128 u32: ccnt[64], rcnt[64]
#define OFF_HDR  (OFF_CTR + 128 * 4)                 // 64*2 u32 {b1, cb1}
#define OFF_CAND (OFF_HDR + 128 * 4)                 // 64*512 f32
#define OFF_RECI (OFF_CAND + S_FRAMES * CAPC * 4)    // 64*4096 u32
#define OFF_RECV (OFF_RECI + S_FRAMES * CAPR * 4)    // 64*4096 f32
#define OFF_MED  (OFF_RECV + S_FRAMES * CAPR * 4)    // 64 f32
#define OFF_FBB  (OFF_MED + 256)                     // 64*6 f32 per-frame bbox
#define OFF_VSL  (((OFF_FBB + S_FRAMES * 6 * 4) + 15) & ~15) // voxel slices 19.1 MB

__device__ __forceinline__ int conf_bin(float v) {
    int b = (int)(v * (float)NBINS);
    return b < 0 ? 0 : (b > NBINS - 1 ? NBINS - 1 : b);
}
__device__ __forceinline__ uint32_t encf(float f) {
    uint32_t u = __float_as_uint(f);
    return (u & 0x80000000u) ? ~u : (u | 0x80000000u);
}
__device__ __forceinline__ float decf(uint32_t e) {
    uint32_t u = (e & 0x80000000u) ? (e & 0x7FFFFFFFu) : ~e;
    return __uint_as_float(u);
}

// K1: the single cold 151 MB pass. Per block: fine hist (LDS), coarse-bin xyz minmax
// (LDS, encoded u32 atomics), complexity sums. Also zeroes the append counters.
__global__ __launch_bounds__(256) void k_pass1(const float* __restrict__ conf,
                                               const float* __restrict__ pts,
                                               uint32_t* __restrict__ hsl,
                                               uint32_t* __restrict__ csl,
                                               double* __restrict__ pbd,
                                               uint32_t* __restrict__ pbc,
                                               uint32_t* __restrict__ ctr) {
    int f = blockIdx.x >> 3, chunk = blockIdx.x & 7;
    __shared__ uint32_t h[NBINS];       // 16 KB
    __shared__ uint32_t cmn[192], cmx[192];
    for (int i = threadIdx.x; i < NBINS; i += 256) h[i] = 0;
    for (int i = threadIdx.x; i < 192; i += 256) { cmn[i] = 0xFFFFFFFFu; cmx[i] = 0u; }
    if (chunk == 0 && threadIdx.x < 2) ctr[f + threadIdx.x * 64] = 0u; // ccnt/rcnt for k_resolve
    __syncthreads();

    const size_t base = (size_t)f * NPF + (size_t)chunk * CHK;
    const float4* c4 = (const float4*)(conf + base);
    const float4* p4 = (const float4*)(pts + base * 3);
    double s1 = 0.0, s2 = 0.0;
    uint32_t cnt = 0;
    for (int i = threadIdx.x; i < G4; i += 256) {
        float4 cc = c4[i];
        float4 a = p4[3 * (size_t)i], b = p4[3 * (size_t)i + 1], d = p4[3 * (size_t)i + 2];
        float cv[4] = {cc.x, cc.y, cc.z, cc.w};
        float v[12] = {a.x, a.y, a.z, a.w, b.x, b.y, b.z, b.w, d.x, d.y, d.z, d.w};
        #pragma unroll
        for (int j = 0; j < 4; j++) {
            float c = cv[j];
            int fb = conf_bin(c);
            atomicAdd(&h[fb], 1u);
            if (c > 0.1f) {
                float x = v[3 * j], y = v[3 * j + 1], z = v[3 * j + 2];
                float dd = sqrtf(x * x + y * y + z * z);
                s1 += (double)dd;
                s2 += (double)dd * (double)dd;
                cnt++;
                int cb3 = (fb >> 6) * 3;
                atomicMin(&cmn[cb3 + 0], encf(x));
                atomicMin(&cmn[cb3 + 1], encf(y));
                atomicMin(&cmn[cb3 + 2], encf(z));
                atomicMax(&cmx[cb3 + 0], encf(x));
                atomicMax(&cmx[cb3 + 1], encf(y));
                atomicMax(&cmx[cb3 + 2], encf(z));
            }
        }
    }
    __syncthreads();
    uint32_t* gh = hsl + (size_t)blockIdx.x * NBINS;
    for (int i = threadIdx.x; i < NBINS; i += 256) gh[i] = h[i];
    uint32_t* gc = csl + (size_t)blockIdx.x * 384;
    for (int i = threadIdx.x; i < 192; i += 256) { gc[i] = cmn[i]; gc[192 + i] = cmx[i]; }

    for (int o = 32; o > 0; o >>= 1) {
        s1 += __shfl_xor(s1, o); s2 += __shfl_xor(s2, o); cnt += __shfl_xor(cnt, o);
    }
    __shared__ double rd[2][4];
    __shared__ uint32_t rc[4];
    int wave = threadIdx.x >> 6, lane = threadIdx.x & 63;
    if (lane == 0) { rd[0][wave] = s1; rd[1][wave] = s2; rc[wave] = cnt; }
    __syncthreads();
    if (threadIdx.x == 0) {
        pbd[2 * (size_t)blockIdx.x]     = rd[0][0] + rd[0][1] + rd[0][2] + rd[0][3];
        pbd[2 * (size_t)blockIdx.x + 1] = rd[1][0] + rd[1][1] + rd[1][2] + rd[1][3];
        pbc[blockIdx.x] = rc[0] + rc[1] + rc[2] + rc[3];
    }
}

// K2: fold hist slices + findbin (redundant per block, consistent); warm re-scan of own
// conf chunk appending rank-bin candidate values + med-coarse-bin records (idx,val).
__global__ __launch_bounds__(1024) void k_resolve(const float* __restrict__ conf,
                                                  const uint32_t* __restrict__ hsl,
                                                  uint32_t* __restrict__ ctr,
                                                  uint32_t* __restrict__ hdr,
                                                  float* __restrict__ cand,
                                                  uint32_t* __restrict__ reci,
                                                  float* __restrict__ recv) {
    int f = blockIdx.x >> 3, chunk = blockIdx.x & 7;
    const int tid = threadIdx.x;
    __shared__ uint32_t h[NBINS];
    __shared__ uint32_t wsum[16], wexcl[16];
    __shared__ uint32_t binfo[2];
    const uint32_t* hb = hsl + (size_t)(f * 8) * NBINS;
    for (int i = tid; i < NBINS; i += 1024) {
        uint32_t s = 0;
        #pragma unroll
        for (int k = 0; k < 8; k++) s += hb[(size_t)k * NBINS + i];
        h[i] = s;
    }
    __syncthreads();
    const int base = tid * 4;
    uint32_t s = h[base] + h[base + 1] + h[base + 2] + h[base + 3];
    const uint32_t lane = tid & 63, wave = tid >> 6;
    uint32_t scan = s;
    for (int o = 1; o < 64; o <<= 1) {
        uint32_t t = __shfl_up(scan, o);
        if (lane >= o) scan += t;
    }
    if (lane == 63) wsum[wave] = scan;
    __syncthreads();
    if (tid == 0) {
        uint32_t run = 0;
        for (int w = 0; w < 16; w++) { wexcl[w] = run; run += wsum[w]; }
    }
    __syncthreads();
    uint32_t excl = wexcl[wave] + (scan - s);
    if (R1 >= excl && R1 < excl + s) {
        uint32_t cum = excl;
        #pragma unroll
        for (int j = 0; j < 4; j++) {
            uint32_t c2 = h[base + j];
            if (R1 < cum + c2) { binfo[0] = (uint32_t)(base + j); binfo[1] = cum; break; }
            cum += c2;
        }
    }
    __syncthreads();
    const int b1 = (int)binfo[0];
    const int bc = b1 >> 6;
    if (chunk == 0 && tid < 2) hdr[f * 2 + tid] = binfo[tid];

    uint32_t* ccnt = &ctr[f];
    uint32_t* rcnt = &ctr[64 + f];
    const float4* c4 = (const float4*)(conf + (size_t)f * NPF + (size_t)chunk * CHK);
    for (int i = tid; i < G4; i += 1024) {
        float4 v = c4[i];
        float vv[4] = {v.x, v.y, v.z, v.w};
        #pragma unroll
        for (int j = 0; j < 4; j++) {
            int fb = conf_bin(vv[j]);
            if (fb == b1) {
                uint32_t k = atomicAdd(ccnt, 1u);
                if (k < CAPC) cand[(size_t)f * CAPC + k] = vv[j];
            }
            if ((fb >> 6) == bc) {
                uint32_t k = atomicAdd(rcnt, 1u);
                if (k < CAPR) {
                    reci[(size_t)f * CAPR + k] = (uint32_t)(chunk * CHK + i * 4 + j);
                    recv[(size_t)f * CAPR + k] = vv[j];
                }
            }
        }
    }
}

// K3: per frame — rank-select median; exact bbox = merged coarse bins (b>bc) +
// filtered gather of med-coarse-bin records.
__global__ __launch_bounds__(1024) void k_frame(const float* __restrict__ pts,
                                                const uint32_t* __restrict__ hdr,
                                                const uint32_t* __restrict__ ctr,
                                                const float* __restrict__ cand,
                                                const uint32_t* __restrict__ reci,
                                                const float* __restrict__ recv,
                                                const uint32_t* __restrict__ csl,
                                                float* __restrict__ med,
                                                float* __restrict__ fbb) {
    int f = blockIdx.x;
    const int tid = threadIdx.x;
    __shared__ float cbuf[CAPC];
    __shared__ float smed;
    int b1 = (int)hdr[f * 2];
    uint32_t cb1 = hdr[f * 2 + 1];
    int bc = b1 >> 6;
    int m = (int)min(ctr[f], (uint32_t)CAPC);
    for (int i = tid; i < m; i += 1024) cbuf[i] = cand[(size_t)f * CAPC + i];
    __syncthreads();
    int target = (int)(R1 - cb1);
    for (int i = tid; i < m; i += 1024) {
        float v = cbuf[i];
        int r = 0;
        for (int j = 0; j < m; j++) {
            float w = cbuf[j];
            r += (w < v) || (w == v && j < i);
        }
        if (r == target) { smed = v; med[f] = v; }
    }
    __syncthreads();
    float mv = smed;

    float mnx = 1e30f, mny = 1e30f, mnz = 1e30f;
    float mxx = -1e30f, mxy = -1e30f, mxz = -1e30f;
    int rn = (int)min(ctr[64 + f], (uint32_t)CAPR);
    for (int k = tid; k < rn; k += 1024) {
        float v = recv[(size_t)f * CAPR + k];
        if (v > 0.1f && v >= mv) {
            size_t idx = ((size_t)f * NPF + reci[(size_t)f * CAPR + k]) * 3;
            float x = pts[idx], y = pts[idx + 1], z = pts[idx + 2];
            mnx = fminf(mnx, x); mny = fminf(mny, y); mnz = fminf(mnz, z);
            mxx = fmaxf(mxx, x); mxy = fmaxf(mxy, y); mxz = fmaxf(mxz, z);
        }
    }
    // merged coarse bins strictly above bc (all points there have c >= med > 0.1)
    if (tid < 64 && tid > bc) {
        uint32_t emn[3] = {0xFFFFFFFFu, 0xFFFFFFFFu, 0xFFFFFFFFu};
        uint32_t emx[3] = {0u, 0u, 0u};
        for (int sI = 0; sI < 8; sI++) {
            const uint32_t* gc = csl + (size_t)(f * 8 + sI) * 384;
            #pragma unroll
            for (int k = 0; k < 3; k++) {
                emn[k] = min(emn[k], gc[tid * 3 + k]);
                emx[k] = max(emx[k], gc[192 + tid * 3 + k]);
            }
        }
        if (emn[0] != 0xFFFFFFFFu) {
            mnx = fminf(mnx, decf(emn[0])); mny = fminf(mny, decf(emn[1]));
            mnz = fminf(mnz, decf(emn[2]));
            mxx = fmaxf(mxx, decf(emx[0])); mxy = fmaxf(mxy, decf(emx[1]));
            mxz = fmaxf(mxz, decf(emx[2]));
        }
    }
    for (int o = 32; o > 0; o >>= 1) {
        mnx = fminf(mnx, __shfl_xor(mnx, o)); mny = fminf(mny, __shfl_xor(mny, o));
        mnz = fminf(mnz, __shfl_xor(mnz, o));
        mxx = fmaxf(mxx, __shfl_xor(mxx, o)); mxy = fmaxf(mxy, __shfl_xor(mxy, o));
        mxz = fmaxf(mxz, __shfl_xor(mxz, o));
    }
    __shared__ float rf[6][16];
    int wave = tid >> 6, lane = tid & 63;
    if (lane == 0) {
        rf[0][wave] = mnx; rf[1][wave] = mny; rf[2][wave] = mnz;
        rf[3][wave] = mxx; rf[4][wave] = mxy; rf[5][wave] = mxz;
    }
    __syncthreads();
    if (tid == 0) {
        float o0 = rf[0][0], o1 = rf[1][0], o2 = rf[2][0];
        float o3 = rf[3][0], o4 = rf[4][0], o5 = rf[5][0];
        for (int w = 1; w < 16; w++) {
            o0 = fminf(o0, rf[0][w]); o1 = fminf(o1, rf[1][w]); o2 = fminf(o2, rf[2][w]);
            o3 = fmaxf(o3, rf[3][w]); o4 = fmaxf(o4, rf[4][w]); o5 = fmaxf(o5, rf[5][w]);
        }
        fbb[f * 6 + 0] = o0; fbb[f * 6 + 1] = o1; fbb[f * 6 + 2] = o2;
        fbb[f * 6 + 3] = o3; fbb[f * 6 + 4] = o4; fbb[f * 6 + 5] = o5;
    }
}

// K4: 3-scale LDS voxel bitmaps -> private slice; prologue folds the 64 frame bboxes
__global__ __launch_bounds__(256) void k_voxel(const float* __restrict__ pts,
                                               const float* __restrict__ conf,
                                               const float* __restrict__ med,
                                               const float* __restrict__ fbb,
                                               uint32_t* __restrict__ vsl) {
    int f = blockIdx.x >> 3;
    int chunk = blockIdx.x & 7;
    __shared__ __align__(16) uint32_t bm[WORDS_BM];
    for (int i = threadIdx.x; i < WORDS_BM; i += 256) bm[i] = 0;
    float pmnx = 1e30f, pmny = 1e30f, pmnz = 1e30f;
    float pmxx = -1e30f, pmxy = -1e30f, pmxz = -1e30f;
    for (int i = 0; i < S_FRAMES; i++) {
        pmnx = fminf(pmnx, fbb[i * 6 + 0]); pmny = fminf(pmny, fbb[i * 6 + 1]);
        pmnz = fminf(pmnz, fbb[i * 6 + 2]);
        pmxx = fmaxf(pmxx, fbb[i * 6 + 3]); pmxy = fmaxf(pmxy, fbb[i * 6 + 4]);
        pmxz = fmaxf(pmxz, fbb[i * 6 + 5]);
    }
    float ex = pmxx - pmnx, ey = pmxy - pmny, ez = pmxz - pmnz;
    float me = fminf(ex, fminf(ey, ez));
    float i40 = 40.0f / me, i20 = 20.0f / me, i10 = 10.0f / me;
    float q = med[f];
    __syncthreads();
    const size_t base = (size_t)f * NPF + (size_t)chunk * CHK;
    const float4* c4 = (const float4*)(conf + base);
    const float4* p4 = (const float4*)(pts + base * 3);
    for (int i = threadIdx.x; i < G4; i += 256) {
        float4 cc = c4[i];
        float4 a = p4[3 * (size_t)i], b = p4[3 * (size_t)i + 1], d = p4[3 * (size_t)i + 2];
        float cv[4] = {cc.x, cc.y, cc.z, cc.w};
        float v[12] = {a.x, a.y, a.z, a.w, b.x, b.y, b.z, b.w, d.x, d.y, d.z, d.w};
        #pragma unroll
        for (int j = 0; j < 4; j++) {
            float c = cv[j];
            if (c > 0.1f && c >= q) {
                float x = v[3 * j] - pmnx, y = v[3 * j + 1] - pmny, z = v[3 * j + 2] - pmnz;
                int cx, cy, cz, bit;
                cx = (int)floorf(x * i40); cy = (int)floorf(y * i40); cz = (int)floorf(z * i40);
                cx = min(max(cx, 0), 63); cy = min(max(cy, 0), 63); cz = min(max(cz, 0), 63);
                bit = (cx << 12) | (cy << 6) | cz;
                atomicOr(&bm[bit >> 5], 1u << (bit & 31));
                cx = (int)floorf(x * i20); cy = (int)floorf(y * i20); cz = (int)floorf(z * i20);
                cx = min(max(cx, 0), 31); cy = min(max(cy, 0), 31); cz = min(max(cz, 0), 31);
                bit = (cx << 10) | (cy << 5) | cz;
                atomicOr(&bm[8192 + (bit >> 5)], 1u << (bit & 31));
                cx = (int)floorf(x * i10); cy = (int)floorf(y * i10); cz = (int)floorf(z * i10);
                cx = min(max(cx, 0), 15); cy = min(max(cy, 0), 15); cz = min(max(cz, 0), 15);
                bit = (cx << 8) | (cy << 4) | cz;
                atomicOr(&bm[9216 + (bit >> 5)], 1u << (bit & 31));
            }
        }
    }
    __syncthreads();
    uint4* dst = (uint4*)(vsl + (size_t)blockIdx.x * WORDS_BM);
    const uint4* src = (const uint4*)bm;
    for (int i = threadIdx.x; i < WORDS_BM / 4; i += 256) dst[i] = src[i];
}

// K5: OR 8 slices per frame, popcount -> counts; f==0 folds sums partials -> complexity
__global__ __launch_bounds__(256) void k_final(const uint32_t* __restrict__ vsl,
                                               const double* __restrict__ pbd,
                                               const uint32_t* __restrict__ pbc,
                                               float* __restrict__ out) {
    int f = blockIdx.x;
    uint32_t c40 = 0, c20 = 0, c10 = 0;
    const uint32_t* fb = vsl + (size_t)(f * 8) * WORDS_BM;
    for (int i = threadIdx.x; i < WORDS_BM / 4; i += 256) {
        uint4 w = ((const uint4*)fb)[i];
        #pragma unroll
        for (int k = 1; k < 8; k++) {
            uint4 u = ((const uint4*)(fb + (size_t)k * WORDS_BM))[i];
            w.x |= u.x; w.y |= u.y; w.z |= u.z; w.w |= u.w;
        }
        uint32_t pc = __popc(w.x) + __popc(w.y) + __popc(w.z) + __popc(w.w);
        if (i < 2048) c40 += pc;
        else if (i < 2304) c20 += pc;
        else c10 += pc;
    }
    for (int o = 32; o > 0; o >>= 1) {
        c40 += __shfl_xor(c40, o);
        c20 += __shfl_xor(c20, o);
        c10 += __shfl_xor(c10, o);
    }
    __shared__ uint32_t red[3][4];
    int wave = threadIdx.x >> 6, lane = threadIdx.x & 63;
    if (lane == 0) { red[0][wave] = c40; red[1][wave] = c20; red[2][wave] = c10; }
    __syncthreads();
    if (threadIdx.x == 0) {
        uint32_t t40 = red[0][0] + red[0][1] + red[0][2] + red[0][3];
        uint32_t t20 = red[1][0] + red[1][1] + red[1][2] + red[1][3];
        uint32_t t10 = red[2][0] + red[2][1] + red[2][2] + red[2][3];
        out[0 * S_FRAMES + f] = (float)t10;
        out[1 * S_FRAMES + f] = (float)t20;
        out[2 * S_FRAMES + f] = (float)t40;
        out[3 * S_FRAMES + f] = (float)t20; // adaptive lambda == 20
    }
    if (f == 0) {
        double s1 = 0.0, s2 = 0.0;
        uint32_t cnt = 0;
        for (int b = threadIdx.x; b < NB1; b += 256) {
            s1 += pbd[2 * (size_t)b];
            s2 += pbd[2 * (size_t)b + 1];
            cnt += pbc[b];
        }
        for (int o = 32; o > 0; o >>= 1) {
            s1 += __shfl_xor(s1, o); s2 += __shfl_xor(s2, o); cnt += __shfl_xor(cnt, o);
        }
        __shared__ double rd[2][4];
        __shared__ uint32_t rc2[4];
        if (lane == 0) { rd[0][wave] = s1; rd[1][wave] = s2; rc2[wave] = cnt; }
        __syncthreads();
        if (threadIdx.x == 0) {
            double S1 = rd[0][0] + rd[0][1] + rd[0][2] + rd[0][3];
            double S2 = rd[1][0] + rd[1][1] + rd[1][2] + rd[1][3];
            double n = (double)(rc2[0] + rc2[1] + rc2[2] + rc2[3]);
            double mean = S1 / n;
            double var = (S2 - n * mean * mean) / (n - 1.0);
            out[4 * S_FRAMES] = (float)(sqrt(var) * (n / (double)TOT));
        }
    }
}

extern "C" void kernel_launch(void* const* d_in, const int* in_sizes, int n_in,
                              void* d_out, int out_size, void* d_ws, size_t ws_size,
                              hipStream_t stream) {
    const float* pts  = (const float*)d_in[0];
    const float* conf = (const float*)d_in[1];
    float* out = (float*)d_out;
    char* ws = (char*)d_ws;
    uint32_t* hsl  = (uint32_t*)(ws + OFF_HSL);
    uint32_t* csl  = (uint32_t*)(ws + OFF_CSL);
    double*   pbd  = (double*)(ws + OFF_PBD);
    uint32_t* pbc  = (uint32_t*)(ws + OFF_PBC);
    uint32_t* ctr  = (uint32_t*)(ws + OFF_CTR);
    uint32_t* hdr  = (uint32_t*)(ws + OFF_HDR);
    float*    cand = (float*)(ws + OFF_CAND);
    uint32_t* reci = (uint32_t*)(ws + OFF_RECI);
    float*    recv = (float*)(ws + OFF_RECV);
    float*    med  = (float*)(ws + OFF_MED);
    float*    fbb  = (float*)(ws + OFF_FBB);
    uint32_t* vsl  = (uint32_t*)(ws + OFF_VSL);

    k_pass1  <<<NB1,      256,  0, stream>>>(conf, pts, hsl, csl, pbd, pbc, ctr);
    k_resolve<<<NB1,      1024, 0, stream>>>(conf, hsl, ctr, hdr, cand, reci, recv);
    k_frame  <<<S_FRAMES, 1024, 0, stream>>>(pts, hdr, ctr, cand, reci, recv, csl, med, fbb);
    k_voxel  <<<NB1,      256,  0, stream>>>(pts, conf, med, fbb, vsl);
    k_final  <<<S_FRAMES, 256,  0, stream>>>(vsl, pbd, pbc, out);
}

// Round 8
// 105.866 us; speedup vs baseline: 5.1661x; 5.1661x over previous
//
#include <hip/hip_runtime.h>
#include <cstdint>

#define S_FRAMES 64
#define NPF      147456           // 384*384
#define TOT      (S_FRAMES * NPF) // 9437184
#define NBINS    4096
#define R1       73728u           // valid = c >= sorted[R1] (== c >= median, exactly)
#define NB1      512              // 8 blocks/frame for the big passes
#define CHK      (NPF / 8)        // 18432 points per chunk
#define G4       (CHK / 4)        // 4608 float4 groups per chunk
#define CAPC     512
#define CAPR     4096
#define LCAPR    1024             // per-block LDS staging cap (records)
#define LCAPC    128              // per-block LDS staging cap (candidates)
#define WORDS_BM 9344             // 8192 (dim64,λ40) + 1024 (dim32,λ20) + 128 (dim16,λ10)

// ---- workspace layout (bytes) ----
#define OFF_HSL  0                                   // 512*4096*4 = 8 MB hist slices
#define OFF_CSL  (OFF_HSL + NB1 * NBINS * 4)         // 512*384*4 coarse minmax slices
#define OFF_PBD  (OFF_CSL + NB1 * 384 * 4)           // 512*2 f64 sums partials
#define OFF_PBC  (OFF_PBD + NB1 * 16)                // 512 u32 count partials
#define OFF_CTR  (OFF_PBC + NB1 * 4)                 // 128 u32: ccnt[64], rcnt[64]
#define OFF_HDR  (OFF_CTR + 128 * 4)                 // 64*2 u32 {b1, cb1}
#define OFF_CAND (OFF_HDR + 128 * 4)                 // 64*512 f32
#define OFF_RECI (OFF_CAND + S_FRAMES * CAPC * 4)    // 64*4096 u32
#define OFF_RECV (OFF_RECI + S_FRAMES * CAPR * 4)    // 64*4096 f32
#define OFF_MED  (OFF_RECV + S_FRAMES * CAPR * 4)    // 64 f32
#define OFF_FBB  (OFF_MED + 256)                     // 64*6 f32 per-frame bbox
#define OFF_VSL  (((OFF_FBB + S_FRAMES * 6 * 4) + 15) & ~15) // voxel slices 19.1 MB

__device__ __forceinline__ int conf_bin(float v) {
    int b = (int)(v * (float)NBINS);
    return b < 0 ? 0 : (b > NBINS - 1 ? NBINS - 1 : b);
}
__device__ __forceinline__ uint32_t encf(float f) {
    uint32_t u = __float_as_uint(f);
    return (u & 0x80000000u) ? ~u : (u | 0x80000000u);
}
__device__ __forceinline__ float decf(uint32_t e) {
    uint32_t u = (e & 0x80000000u) ? (e & 0x7FFFFFFFu) : ~e;
    return __uint_as_float(u);
}

// K1: the single cold 151 MB pass. Per block: fine hist (LDS), coarse-bin xyz minmax
// (LDS, encoded u32 atomics), complexity sums. Also zeroes the append counters.
__global__ __launch_bounds__(256) void k_pass1(const float* __restrict__ conf,
                                               const float* __restrict__ pts,
                                               uint32_t* __restrict__ hsl,
                                               uint32_t* __restrict__ csl,
                                               double* __restrict__ pbd,
                                               uint32_t* __restrict__ pbc,
                                               uint32_t* __restrict__ ctr) {
    int f = blockIdx.x >> 3, chunk = blockIdx.x & 7;
    __shared__ uint32_t h[NBINS];       // 16 KB
    __shared__ uint32_t cmn[192], cmx[192];
    for (int i = threadIdx.x; i < NBINS; i += 256) h[i] = 0;
    for (int i = threadIdx.x; i < 192; i += 256) { cmn[i] = 0xFFFFFFFFu; cmx[i] = 0u; }
    if (chunk == 0 && threadIdx.x < 2) ctr[f + threadIdx.x * 64] = 0u; // ccnt/rcnt for k_resolve
    __syncthreads();

    const size_t base = (size_t)f * NPF + (size_t)chunk * CHK;
    const float4* c4 = (const float4*)(conf + base);
    const float4* p4 = (const float4*)(pts + base * 3);
    double s1 = 0.0, s2 = 0.0;
    uint32_t cnt = 0;
    for (int i = threadIdx.x; i < G4; i += 256) {
        float4 cc = c4[i];
        float4 a = p4[3 * (size_t)i], b = p4[3 * (size_t)i + 1], d = p4[3 * (size_t)i + 2];
        float cv[4] = {cc.x, cc.y, cc.z, cc.w};
        float v[12] = {a.x, a.y, a.z, a.w, b.x, b.y, b.z, b.w, d.x, d.y, d.z, d.w};
        #pragma unroll
        for (int j = 0; j < 4; j++) {
            float c = cv[j];
            int fb = conf_bin(c);
            atomicAdd(&h[fb], 1u);
            if (c > 0.1f) {
                float x = v[3 * j], y = v[3 * j + 1], z = v[3 * j + 2];
                float dd = sqrtf(x * x + y * y + z * z);
                s1 += (double)dd;
                s2 += (double)dd * (double)dd;
                cnt++;
                int cb3 = (fb >> 6) * 3;
                atomicMin(&cmn[cb3 + 0], encf(x));
                atomicMin(&cmn[cb3 + 1], encf(y));
                atomicMin(&cmn[cb3 + 2], encf(z));
                atomicMax(&cmx[cb3 + 0], encf(x));
                atomicMax(&cmx[cb3 + 1], encf(y));
                atomicMax(&cmx[cb3 + 2], encf(z));
            }
        }
    }
    __syncthreads();
    uint32_t* gh = hsl + (size_t)blockIdx.x * NBINS;
    for (int i = threadIdx.x; i < NBINS; i += 256) gh[i] = h[i];
    uint32_t* gc = csl + (size_t)blockIdx.x * 384;
    for (int i = threadIdx.x; i < 192; i += 256) { gc[i] = cmn[i]; gc[192 + i] = cmx[i]; }

    for (int o = 32; o > 0; o >>= 1) {
        s1 += __shfl_xor(s1, o); s2 += __shfl_xor(s2, o); cnt += __shfl_xor(cnt, o);
    }
    __shared__ double rd[2][4];
    __shared__ uint32_t rc[4];
    int wave = threadIdx.x >> 6, lane = threadIdx.x & 63;
    if (lane == 0) { rd[0][wave] = s1; rd[1][wave] = s2; rc[wave] = cnt; }
    __syncthreads();
    if (threadIdx.x == 0) {
        pbd[2 * (size_t)blockIdx.x]     = rd[0][0] + rd[0][1] + rd[0][2] + rd[0][3];
        pbd[2 * (size_t)blockIdx.x + 1] = rd[1][0] + rd[1][1] + rd[1][2] + rd[1][3];
        pbc[blockIdx.x] = rc[0] + rc[1] + rc[2] + rc[3];
    }
}

// K2: fold hist slices + findbin (redundant per block, consistent); warm re-scan of own
// conf chunk. Appends are LDS-STAGED: one global atomicAdd per block per counter
// (round-7 post-mortem: per-hit same-address global atomics serialized at ~200ns -> 459us).
__global__ __launch_bounds__(1024) void k_resolve(const float* __restrict__ conf,
                                                  const uint32_t* __restrict__ hsl,
                                                  uint32_t* __restrict__ ctr,
                                                  uint32_t* __restrict__ hdr,
                                                  float* __restrict__ cand,
                                                  uint32_t* __restrict__ reci,
                                                  float* __restrict__ recv) {
    int f = blockIdx.x >> 3, chunk = blockIdx.x & 7;
    const int tid = threadIdx.x;
    __shared__ uint32_t h[NBINS];
    __shared__ uint32_t wsum[16], wexcl[16];
    __shared__ uint32_t binfo[2];
    const uint32_t* hb = hsl + (size_t)(f * 8) * NBINS;
    for (int i = tid; i < NBINS; i += 1024) {
        uint32_t s = 0;
        #pragma unroll
        for (int k = 0; k < 8; k++) s += hb[(size_t)k * NBINS + i];
        h[i] = s;
    }
    __syncthreads();
    const int base = tid * 4;
    uint32_t s = h[base] + h[base + 1] + h[base + 2] + h[base + 3];
    const uint32_t lane = tid & 63, wave = tid >> 6;
    uint32_t scan = s;
    for (int o = 1; o < 64; o <<= 1) {
        uint32_t t = __shfl_up(scan, o);
        if (lane >= o) scan += t;
    }
    if (lane == 63) wsum[wave] = scan;
    __syncthreads();
    if (tid == 0) {
        uint32_t run = 0;
        for (int w = 0; w < 16; w++) { wexcl[w] = run; run += wsum[w]; }
    }
    __syncthreads();
    uint32_t excl = wexcl[wave] + (scan - s);
    if (R1 >= excl && R1 < excl + s) {
        uint32_t cum = excl;
        #pragma unroll
        for (int j = 0; j < 4; j++) {
            uint32_t c2 = h[base + j];
            if (R1 < cum + c2) { binfo[0] = (uint32_t)(base + j); binfo[1] = cum; break; }
            cum += c2;
        }
    }
    __syncthreads();
    const int b1 = (int)binfo[0];
    const int bc = b1 >> 6;
    if (chunk == 0 && tid < 2) hdr[f * 2 + tid] = binfo[tid];

    // LDS staging buffers for appends
    __shared__ uint32_t l_ri[LCAPR];
    __shared__ float    l_rv[LCAPR];
    __shared__ float    l_cv[LCAPC];
    __shared__ uint32_t l_nr, l_nc, g_base_r, g_base_c;
    if (tid == 0) { l_nr = 0u; l_nc = 0u; }
    __syncthreads();

    uint32_t* ccnt = &ctr[f];
    uint32_t* rcnt = &ctr[64 + f];
    const float4* c4 = (const float4*)(conf + (size_t)f * NPF + (size_t)chunk * CHK);
    for (int i = tid; i < G4; i += 1024) {
        float4 v = c4[i];
        float vv[4] = {v.x, v.y, v.z, v.w};
        #pragma unroll
        for (int j = 0; j < 4; j++) {
            int fb = conf_bin(vv[j]);
            if (fb == b1) {
                uint32_t k = atomicAdd(&l_nc, 1u);
                if (k < LCAPC) l_cv[k] = vv[j];
                else { // rare spill
                    uint32_t g = atomicAdd(ccnt, 1u);
                    if (g < CAPC) cand[(size_t)f * CAPC + g] = vv[j];
                }
            }
            if ((fb >> 6) == bc) {
                uint32_t k = atomicAdd(&l_nr, 1u);
                if (k < LCAPR) {
                    l_ri[k] = (uint32_t)(chunk * CHK + i * 4 + j);
                    l_rv[k] = vv[j];
                } else { // rare spill
                    uint32_t g = atomicAdd(rcnt, 1u);
                    if (g < CAPR) {
                        reci[(size_t)f * CAPR + g] = (uint32_t)(chunk * CHK + i * 4 + j);
                        recv[(size_t)f * CAPR + g] = vv[j];
                    }
                }
            }
        }
    }
    __syncthreads();
    if (tid == 0) {
        g_base_c = atomicAdd(ccnt, min(l_nc, (uint32_t)LCAPC));
        g_base_r = atomicAdd(rcnt, min(l_nr, (uint32_t)LCAPR));
    }
    __syncthreads();
    uint32_t nc = min(l_nc, (uint32_t)LCAPC), bcg = g_base_c;
    for (uint32_t i = tid; i < nc; i += 1024) {
        uint32_t g = bcg + i;
        if (g < CAPC) cand[(size_t)f * CAPC + g] = l_cv[i];
    }
    uint32_t nr = min(l_nr, (uint32_t)LCAPR), brg = g_base_r;
    for (uint32_t i = tid; i < nr; i += 1024) {
        uint32_t g = brg + i;
        if (g < CAPR) {
            reci[(size_t)f * CAPR + g] = l_ri[i];
            recv[(size_t)f * CAPR + g] = l_rv[i];
        }
    }
}

// K3: per frame — rank-select median; exact bbox = merged coarse bins (b>bc) +
// filtered gather of med-coarse-bin records.
__global__ __launch_bounds__(1024) void k_frame(const float* __restrict__ pts,
                                                const uint32_t* __restrict__ hdr,
                                                const uint32_t* __restrict__ ctr,
                                                const float* __restrict__ cand,
                                                const uint32_t* __restrict__ reci,
                                                const float* __restrict__ recv,
                                                const uint32_t* __restrict__ csl,
                                                float* __restrict__ med,
                                                float* __restrict__ fbb) {
    int f = blockIdx.x;
    const int tid = threadIdx.x;
    __shared__ float cbuf[CAPC];
    __shared__ float smed;
    int b1 = (int)hdr[f * 2];
    uint32_t cb1 = hdr[f * 2 + 1];
    int bc = b1 >> 6;
    int m = (int)min(ctr[f], (uint32_t)CAPC);
    for (int i = tid; i < m; i += 1024) cbuf[i] = cand[(size_t)f * CAPC + i];
    __syncthreads();
    int target = (int)(R1 - cb1);
    for (int i = tid; i < m; i += 1024) {
        float v = cbuf[i];
        int r = 0;
        for (int j = 0; j < m; j++) {
            float w = cbuf[j];
            r += (w < v) || (w == v && j < i);
        }
        if (r == target) { smed = v; med[f] = v; }
    }
    __syncthreads();
    float mv = smed;

    float mnx = 1e30f, mny = 1e30f, mnz = 1e30f;
    float mxx = -1e30f, mxy = -1e30f, mxz = -1e30f;
    int rn = (int)min(ctr[64 + f], (uint32_t)CAPR);
    for (int k = tid; k < rn; k += 1024) {
        float v = recv[(size_t)f * CAPR + k];
        if (v > 0.1f && v >= mv) {
            size_t idx = ((size_t)f * NPF + reci[(size_t)f * CAPR + k]) * 3;
            float x = pts[idx], y = pts[idx + 1], z = pts[idx + 2];
            mnx = fminf(mnx, x); mny = fminf(mny, y); mnz = fminf(mnz, z);
            mxx = fmaxf(mxx, x); mxy = fmaxf(mxy, y); mxz = fmaxf(mxz, z);
        }
    }
    // merged coarse bins strictly above bc (all points there have c >= med > 0.1)
    if (tid < 64 && tid > bc) {
        uint32_t emn[3] = {0xFFFFFFFFu, 0xFFFFFFFFu, 0xFFFFFFFFu};
        uint32_t emx[3] = {0u, 0u, 0u};
        for (int sI = 0; sI < 8; sI++) {
            const uint32_t* gc = csl + (size_t)(f * 8 + sI) * 384;
            #pragma unroll
            for (int k = 0; k < 3; k++) {
                emn[k] = min(emn[k], gc[tid * 3 + k]);
                emx[k] = max(emx[k], gc[192 + tid * 3 + k]);
            }
        }
        if (emn[0] != 0xFFFFFFFFu) {
            mnx = fminf(mnx, decf(emn[0])); mny = fminf(mny, decf(emn[1]));
            mnz = fminf(mnz, decf(emn[2]));
            mxx = fmaxf(mxx, decf(emx[0])); mxy = fmaxf(mxy, decf(emx[1]));
            mxz = fmaxf(mxz, decf(emx[2]));
        }
    }
    for (int o = 32; o > 0; o >>= 1) {
        mnx = fminf(mnx, __shfl_xor(mnx, o)); mny = fminf(mny, __shfl_xor(mny, o));
        mnz = fminf(mnz, __shfl_xor(mnz, o));
        mxx = fmaxf(mxx, __shfl_xor(mxx, o)); mxy = fmaxf(mxy, __shfl_xor(mxy, o));
        mxz = fmaxf(mxz, __shfl_xor(mxz, o));
    }
    __shared__ float rf[6][16];
    int wave = tid >> 6, lane = tid & 63;
    if (lane == 0) {
        rf[0][wave] = mnx; rf[1][wave] = mny; rf[2][wave] = mnz;
        rf[3][wave] = mxx; rf[4][wave] = mxy; rf[5][wave] = mxz;
    }
    __syncthreads();
    if (tid == 0) {
        float o0 = rf[0][0], o1 = rf[1][0], o2 = rf[2][0];
        float o3 = rf[3][0], o4 = rf[4][0], o5 = rf[5][0];
        for (int w = 1; w < 16; w++) {
            o0 = fminf(o0, rf[0][w]); o1 = fminf(o1, rf[1][w]); o2 = fminf(o2, rf[2][w]);
            o3 = fmaxf(o3, rf[3][w]); o4 = fmaxf(o4, rf[4][w]); o5 = fmaxf(o5, rf[5][w]);
        }
        fbb[f * 6 + 0] = o0; fbb[f * 6 + 1] = o1; fbb[f * 6 + 2] = o2;
        fbb[f * 6 + 3] = o3; fbb[f * 6 + 4] = o4; fbb[f * 6 + 5] = o5;
    }
}

// K4: 3-scale LDS voxel bitmaps -> private slice; prologue folds the 64 frame bboxes
__global__ __launch_bounds__(256) void k_voxel(const float* __restrict__ pts,
                                               const float* __restrict__ conf,
                                               const float* __restrict__ med,
                                               const float* __restrict__ fbb,
                                               uint32_t* __restrict__ vsl) {
    int f = blockIdx.x >> 3;
    int chunk = blockIdx.x & 7;
    __shared__ __align__(16) uint32_t bm[WORDS_BM];
    for (int i = threadIdx.x; i < WORDS_BM; i += 256) bm[i] = 0;
    float pmnx = 1e30f, pmny = 1e30f, pmnz = 1e30f;
    float pmxx = -1e30f, pmxy = -1e30f, pmxz = -1e30f;
    for (int i = 0; i < S_FRAMES; i++) {
        pmnx = fminf(pmnx, fbb[i * 6 + 0]); pmny = fminf(pmny, fbb[i * 6 + 1]);
        pmnz = fminf(pmnz, fbb[i * 6 + 2]);
        pmxx = fmaxf(pmxx, fbb[i * 6 + 3]); pmxy = fmaxf(pmxy, fbb[i * 6 + 4]);
        pmxz = fmaxf(pmxz, fbb[i * 6 + 5]);
    }
    float ex = pmxx - pmnx, ey = pmxy - pmny, ez = pmxz - pmnz;
    float me = fminf(ex, fminf(ey, ez));
    float i40 = 40.0f / me, i20 = 20.0f / me, i10 = 10.0f / me;
    float q = med[f];
    __syncthreads();
    const size_t base = (size_t)f * NPF + (size_t)chunk * CHK;
    const float4* c4 = (const float4*)(conf + base);
    const float4* p4 = (const float4*)(pts + base * 3);
    for (int i = threadIdx.x; i < G4; i += 256) {
        float4 cc = c4[i];
        float4 a = p4[3 * (size_t)i], b = p4[3 * (size_t)i + 1], d = p4[3 * (size_t)i + 2];
        float cv[4] = {cc.x, cc.y, cc.z, cc.w};
        float v[12] = {a.x, a.y, a.z, a.w, b.x, b.y, b.z, b.w, d.x, d.y, d.z, d.w};
        #pragma unroll
        for (int j = 0; j < 4; j++) {
            float c = cv[j];
            if (c > 0.1f && c >= q) {
                float x = v[3 * j] - pmnx, y = v[3 * j + 1] - pmny, z = v[3 * j + 2] - pmnz;
                int cx, cy, cz, bit;
                cx = (int)floorf(x * i40); cy = (int)floorf(y * i40); cz = (int)floorf(z * i40);
                cx = min(max(cx, 0), 63); cy = min(max(cy, 0), 63); cz = min(max(cz, 0), 63);
                bit = (cx << 12) | (cy << 6) | cz;
                atomicOr(&bm[bit >> 5], 1u << (bit & 31));
                cx = (int)floorf(x * i20); cy = (int)floorf(y * i20); cz = (int)floorf(z * i20);
                cx = min(max(cx, 0), 31); cy = min(max(cy, 0), 31); cz = min(max(cz, 0), 31);
                bit = (cx << 10) | (cy << 5) | cz;
                atomicOr(&bm[8192 + (bit >> 5)], 1u << (bit & 31));
                cx = (int)floorf(x * i10); cy = (int)floorf(y * i10); cz = (int)floorf(z * i10);
                cx = min(max(cx, 0), 15); cy = min(max(cy, 0), 15); cz = min(max(cz, 0), 15);
                bit = (cx << 8) | (cy << 4) | cz;
                atomicOr(&bm[9216 + (bit >> 5)], 1u << (bit & 31));
            }
        }
    }
    __syncthreads();
    uint4* dst = (uint4*)(vsl + (size_t)blockIdx.x * WORDS_BM);
    const uint4* src = (const uint4*)bm;
    for (int i = threadIdx.x; i < WORDS_BM / 4; i += 256) dst[i] = src[i];
}

// K5: OR 8 slices per frame, popcount -> counts; f==0 folds sums partials -> complexity
__global__ __launch_bounds__(256) void k_final(const uint32_t* __restrict__ vsl,
                                               const double* __restrict__ pbd,
                                               const uint32_t* __restrict__ pbc,
                                               float* __restrict__ out) {
    int f = blockIdx.x;
    uint32_t c40 = 0, c20 = 0, c10 = 0;
    const uint32_t* fb = vsl + (size_t)(f * 8) * WORDS_BM;
    for (int i = threadIdx.x; i < WORDS_BM / 4; i += 256) {
        uint4 w = ((const uint4*)fb)[i];
        #pragma unroll
        for (int k = 1; k < 8; k++) {
            uint4 u = ((const uint4*)(fb + (size_t)k * WORDS_BM))[i];
            w.x |= u.x; w.y |= u.y; w.z |= u.z; w.w |= u.w;
        }
        uint32_t pc = __popc(w.x) + __popc(w.y) + __popc(w.z) + __popc(w.w);
        if (i < 2048) c40 += pc;
        else if (i < 2304) c20 += pc;
        else c10 += pc;
    }
    for (int o = 32; o > 0; o >>= 1) {
        c40 += __shfl_xor(c40, o);
        c20 += __shfl_xor(c20, o);
        c10 += __shfl_xor(c10, o);
    }
    __shared__ uint32_t red[3][4];
    int wave = threadIdx.x >> 6, lane = threadIdx.x & 63;
    if (lane == 0) { red[0][wave] = c40; red[1][wave] = c20; red[2][wave] = c10; }
    __syncthreads();
    if (threadIdx.x == 0) {
        uint32_t t40 = red[0][0] + red[0][1] + red[0][2] + red[0][3];
        uint32_t t20 = red[1][0] + red[1][1] + red[1][2] + red[1][3];
        uint32_t t10 = red[2][0] + red[2][1] + red[2][2] + red[2][3];
        out[0 * S_FRAMES + f] = (float)t10;
        out[1 * S_FRAMES + f] = (float)t20;
        out[2 * S_FRAMES + f] = (float)t40;
        out[3 * S_FRAMES + f] = (float)t20; // adaptive lambda == 20
    }
    if (f == 0) {
        double s1 = 0.0, s2 = 0.0;
        uint32_t cnt = 0;
        for (int b = threadIdx.x; b < NB1; b += 256) {
            s1 += pbd[2 * (size_t)b];
            s2 += pbd[2 * (size_t)b + 1];
            cnt += pbc[b];
        }
        for (int o = 32; o > 0; o >>= 1) {
            s1 += __shfl_xor(s1, o); s2 += __shfl_xor(s2, o); cnt += __shfl_xor(cnt, o);
        }
        __shared__ double rd[2][4];
        __shared__ uint32_t rc2[4];
        if (lane == 0) { rd[0][wave] = s1; rd[1][wave] = s2; rc2[wave] = cnt; }
        __syncthreads();
        if (threadIdx.x == 0) {
            double S1 = rd[0][0] + rd[0][1] + rd[0][2] + rd[0][3];
            double S2 = rd[1][0] + rd[1][1] + rd[1][2] + rd[1][3];
            double n = (double)(rc2[0] + rc2[1] + rc2[2] + rc2[3]);
            double mean = S1 / n;
            double var = (S2 - n * mean * mean) / (n - 1.0);
            out[4 * S_FRAMES] = (float)(sqrt(var) * (n / (double)TOT));
        }
    }
}

extern "C" void kernel_launch(void* const* d_in, const int* in_sizes, int n_in,
                              void* d_out, int out_size, void* d_ws, size_t ws_size,
                              hipStream_t stream) {
    const float* pts  = (const float*)d_in[0];
    const float* conf = (const float*)d_in[1];
    float* out = (float*)d_out;
    char* ws = (char*)d_ws;
    uint32_t* hsl  = (uint32_t*)(ws + OFF_HSL);
    uint32_t* csl  = (uint32_t*)(ws + OFF_CSL);
    double*   pbd  = (double*)(ws + OFF_PBD);
    uint32_t* pbc  = (uint32_t*)(ws + OFF_PBC);
    uint32_t* ctr  = (uint32_t*)(ws + OFF_CTR);
    uint32_t* hdr  = (uint32_t*)(ws + OFF_HDR);
    float*    cand = (float*)(ws + OFF_CAND);
    uint32_t* reci = (uint32_t*)(ws + OFF_RECI);
    float*    recv = (float*)(ws + OFF_RECV);
    float*    med  = (float*)(ws + OFF_MED);
    float*    fbb  = (float*)(ws + OFF_FBB);
    uint32_t* vsl  = (uint32_t*)(ws + OFF_VSL);

    k_pass1  <<<NB1,      256,  0, stream>>>(conf, pts, hsl, csl, pbd, pbc, ctr);
    k_resolve<<<NB1,      1024, 0, stream>>>(conf, hsl, ctr, hdr, cand, reci, recv);
    k_frame  <<<S_FRAMES, 1024, 0, stream>>>(pts, hdr, ctr, cand, reci, recv, csl, med, fbb);
    k_voxel  <<<NB1,      256,  0, stream>>>(pts, conf, med, fbb, vsl);
    k_final  <<<S_FRAMES, 256,  0, stream>>>(vsl, pbd, pbc, out);
}